// Round 8
// baseline (47.821 us; speedup 1.0000x reference)
//
#include <hip/hip_runtime.h>
#include <cstdint>

namespace {

constexpr int kB   = 32;            // batches
constexpr int kN   = 131072;        // points per batch
constexpr int kC   = 6;             // channels
constexpr int TPB  = 256;           // threads per block
constexpr int ROWS_PER_BLK = 512;   // 2 rows per thread
constexpr int BPB  = kN / ROWS_PER_BLK;   // 256 blocks per batch
constexpr int NBLK = kB * BPB;            // 8192 blocks total
constexpr int WAVES = TPB / 64;           // 4
constexpr int F4_PER_BLK = ROWS_PER_BLK * kC / 4;  // 768 float4 per block
constexpr int F2_PER_SLOT = ROWS_PER_BLK * kC / 2; // 1536 float2 per staged slot

__device__ __forceinline__ int waveSum(int v) {
#pragma unroll
    for (int off = 32; off; off >>= 1) v += __shfl_xor(v, off, 64);
    return v;
}

// ---------------- FAST PATH (ws >= ~101 MB): stage compacted rows ----------------

// Pass 1: dense coalesced float4 loads -> LDS -> row reassembly -> classify ->
// write per-block compacted valid rows to ws + per-block count.
__global__ __launch_bounds__(TPB) void k_count_stage(const float* __restrict__ pc,
                                                     const float* __restrict__ tt,
                                                     float* __restrict__ staged,
                                                     int* __restrict__ blkCnt) {
    const int blk  = blockIdx.x;
    const int b    = blk >> 8;          // blk / BPB
    const int tid  = threadIdx.x;
    const int lane = tid & 63;
    const int wv   = tid >> 6;

    const float* T = tt + b * 16;       // uniform -> scalar regs
    const float T0 = T[0], T1 = T[1], T2 = T[2],  T3  = T[3];
    const float T4 = T[4], T5 = T[5], T6 = T[6],  T7  = T[7];
    const float T8 = T[8], T9 = T[9], T10 = T[10], T11 = T[11];

    // Dense, fully-coalesced global reads (lane i -> consecutive 16 B).
    const float4* f4 = (const float4*)pc + (size_t)blk * F4_PER_BLK;
    const float4 qa = f4[tid];
    const float4 qb = f4[tid + 256];
    const float4 qc = f4[tid + 512];

    __shared__ float4 sb[F4_PER_BLK];
    sb[tid] = qa; sb[tid + 256] = qb; sb[tid + 512] = qc;
    __syncthreads();

    // Rows 2*tid, 2*tid+1 = float2[6*tid .. 6*tid+5]
    const float2* s2 = (const float2*)sb;
    const float2 r0a = s2[6 * tid],     r0b = s2[6 * tid + 1], r0c = s2[6 * tid + 2];
    const float2 r1a = s2[6 * tid + 3], r1b = s2[6 * tid + 4], r1c = s2[6 * tid + 5];

    // even row: x,y = r0a ; z,nx = r0b ; ny,nz = r0c
    const float ns0 = (r0b.y + r0c.x) + r0c.y;
    const float px0 = r0a.x * T0 + r0a.y * T4 + r0b.x * T8  + T3;
    const float py0 = r0a.x * T1 + r0a.y * T5 + r0b.x * T9  + T7;
    const float pz0 = r0a.x * T2 + r0a.y * T6 + r0b.x * T10 + T11;
    const bool v0 = (px0 * px0 + py0 * py0 < 1.0f) && (pz0 < 1.0f) && (ns0 != 0.0f);

    // odd row: x,y = r1a ; z,nx = r1b ; ny,nz = r1c
    const float ns1 = (r1b.y + r1c.x) + r1c.y;
    const float px1 = r1a.x * T0 + r1a.y * T4 + r1b.x * T8  + T3;
    const float py1 = r1a.x * T1 + r1a.y * T5 + r1b.x * T9  + T7;
    const float pz1 = r1a.x * T2 + r1a.y * T6 + r1b.x * T10 + T11;
    const bool v1 = (px1 * px1 + py1 * py1 < 1.0f) && (pz1 < 1.0f) && (ns1 != 0.0f);

    const uint64_t m0 = __ballot(v0);   // rows wv*128 + 2*lane
    const uint64_t m1 = __ballot(v1);   // rows wv*128 + 2*lane + 1

    __shared__ uint64_t sm[WAVES * 2];
    if (lane == 0) { sm[wv * 2] = m0; sm[wv * 2 + 1] = m1; }
    __syncthreads();

    if (wv == 0) {
        int v = (lane < 8) ? __popcll(sm[lane]) : 0;
        v = waveSum(v);
        if (lane == 0) blkCnt[blk] = v;
    }

    // In-block stable compaction rank
    int wb = 0;
#pragma unroll
    for (int w = 0; w < WAVES - 1; ++w)
        if (w < wv) wb += __popcll(sm[w * 2]) + __popcll(sm[w * 2 + 1]);
    const uint64_t low = (1ull << lane) - 1ull;
    const int beforeE = __popcll(m0 & low) + __popcll(m1 & low);
    const int rk0 = wb + beforeE;
    const int rk1 = rk0 + (v0 ? 1 : 0);

    float2* st = (float2*)(staged + (size_t)blk * (ROWS_PER_BLK * kC));
    if (v0) { float2* o = st + rk0 * 3; o[0] = r0a; o[1] = r0b; o[2] = r0c; }
    if (v1) { float2* o = st + rk1 * 3; o[0] = r1a; o[1] = r1b; o[2] = r1c; }
}

// Pass 2 (output-centric): each block owns output rows [sub*512,(sub+1)*512) and
// writes them as one dense 16B-aligned float4 stream. Valid rows are gathered
// from staged via binary search over the batch's exclusive prefix (LDS).
__global__ __launch_bounds__(TPB) void k_emit(const float* __restrict__ staged,
                                              const int* __restrict__ blkCnt,
                                              float* __restrict__ out) {
    const int blk  = blockIdx.x;
    const int b    = blk >> 8;
    const int sub  = blk & (BPB - 1);
    const int tid  = threadIdx.x;
    const int lane = tid & 63;
    const int wv   = tid >> 6;

    __shared__ int pre[BPB];        // exclusive prefix of per-block counts
    __shared__ int wsum[WAVES];
    __shared__ int s_tot;

    // Inclusive wave scan of the 256 counts, then cross-wave offsets.
    const int c = blkCnt[b * BPB + tid];
    int v = c;
#pragma unroll
    for (int off = 1; off < 64; off <<= 1) {
        const int u = __shfl_up(v, off, 64);
        if (lane >= off) v += u;
    }
    if (lane == 63) wsum[wv] = v;
    __syncthreads();
    int wbase = 0;
#pragma unroll
    for (int w = 0; w < WAVES - 1; ++w)
        if (w < wv) wbase += wsum[w];
    pre[tid] = wbase + v - c;                 // exclusive prefix
    if (tid == TPB - 1) s_tot = wbase + v;    // batch total
    __syncthreads();
    const int total = s_tot;

    const size_t batchF = (size_t)b * kN * kC;
    const int r0 = sub * ROWS_PER_BLK + 2 * tid;     // thread's two rows

    float2 val[6];
#pragma unroll
    for (int e = 0; e < 2; ++e) {
        const int r = r0 + e;
        float2 x0 = make_float2(0.0f, 0.0f), x1 = x0, x2 = x0;
        if (r < total) {
            int lo = 0, hi = BPB - 1;
#pragma unroll
            for (int it = 0; it < 8; ++it) {          // ceil(log2(256)) = 8
                const int mid = (lo + hi + 1) >> 1;
                if (pre[mid] <= r) lo = mid; else hi = mid - 1;
            }
            const int local = r - pre[lo];
            const float2* s = (const float2*)staged
                            + (size_t)(b * BPB + lo) * F2_PER_SLOT + (size_t)local * 3;
            x0 = s[0]; x1 = s[1]; x2 = s[2];
        }
        val[3 * e]     = x0;
        val[3 * e + 1] = x1;
        val[3 * e + 2] = x2;
    }

    // One dense, 16B-aligned store stream: 3 float4 per thread.
    float4* o4 = (float4*)(out + batchF + (size_t)r0 * kC);
    o4[0] = make_float4(val[0].x, val[0].y, val[1].x, val[1].y);
    o4[1] = make_float4(val[2].x, val[2].y, val[3].x, val[3].y);
    o4[2] = make_float4(val[4].x, val[4].y, val[5].x, val[5].y);
}

// ---------------- FALLBACK PATH (small ws): R6 mask-based kernels ----------------

__global__ __launch_bounds__(TPB) void k_count(const float* __restrict__ pc,
                                               const float* __restrict__ tt,
                                               uint64_t* __restrict__ masks,
                                               int* __restrict__ blkCnt) {
    const int blk  = blockIdx.x;
    const int b    = blk >> 8;
    const int tid  = threadIdx.x;
    const int lane = tid & 63;
    const int wv   = tid >> 6;

    const float* T = tt + b * 16;
    const float T0 = T[0], T1 = T[1], T2 = T[2],  T3  = T[3];
    const float T4 = T[4], T5 = T[5], T6 = T[6],  T7  = T[7];
    const float T8 = T[8], T9 = T[9], T10 = T[10], T11 = T[11];

    const float4* f4 = (const float4*)pc + (size_t)blk * F4_PER_BLK;
    const float4 q0 = f4[3 * tid];
    const float4 q1 = f4[3 * tid + 1];
    const float4 q2 = f4[3 * tid + 2];

    const float ns0 = (q0.w + q1.x) + q1.y;
    const float px0 = q0.x * T0 + q0.y * T4 + q0.z * T8  + T3;
    const float py0 = q0.x * T1 + q0.y * T5 + q0.z * T9  + T7;
    const float pz0 = q0.x * T2 + q0.y * T6 + q0.z * T10 + T11;
    const bool v0 = (px0 * px0 + py0 * py0 < 1.0f) && (pz0 < 1.0f) && (ns0 != 0.0f);

    const float ns1 = (q2.y + q2.z) + q2.w;
    const float px1 = q1.z * T0 + q1.w * T4 + q2.x * T8  + T3;
    const float py1 = q1.z * T1 + q1.w * T5 + q2.x * T9  + T7;
    const float pz1 = q1.z * T2 + q1.w * T6 + q2.x * T10 + T11;
    const bool v1 = (px1 * px1 + py1 * py1 < 1.0f) && (pz1 < 1.0f) && (ns1 != 0.0f);

    const uint64_t m0 = __ballot(v0);
    const uint64_t m1 = __ballot(v1);

    __shared__ uint64_t sm[WAVES * 2];
    if (lane == 0) {
        sm[wv * 2]     = m0;
        sm[wv * 2 + 1] = m1;
        masks[(size_t)blk * 8 + wv * 2]     = m0;
        masks[(size_t)blk * 8 + wv * 2 + 1] = m1;
    }
    __syncthreads();
    if (wv == 0) {
        int v = (lane < 8) ? __popcll(sm[lane]) : 0;
        v = waveSum(v);
        if (lane == 0) blkCnt[blk] = v;
    }
}

__global__ __launch_bounds__(TPB) void k_scatter(const float* __restrict__ pc,
                                                 const uint64_t* __restrict__ masks,
                                                 const int* __restrict__ blkCnt,
                                                 float* __restrict__ out) {
    const int blk  = blockIdx.x;
    const int b    = blk >> 8;
    const int sub  = blk & (BPB - 1);
    const int tid  = threadIdx.x;
    const int lane = tid & 63;
    const int wv   = tid >> 6;

    __shared__ uint64_t sm[8];
    __shared__ int sRed[2 * WAVES];

    if (tid < 8) sm[tid] = masks[(size_t)blk * 8 + tid];

    const int c = blkCnt[b * BPB + tid];
    const int pw = waveSum((tid < sub) ? c : 0);
    const int tw = waveSum(c);
    if (lane == 0) { sRed[wv] = pw; sRed[WAVES + wv] = tw; }
    __syncthreads();
    const int blockBase = (sRed[0] + sRed[1]) + (sRed[2] + sRed[3]);
    const int total     = (sRed[4] + sRed[5]) + (sRed[6] + sRed[7]);

    const uint64_t m0 = sm[wv * 2], m1 = sm[wv * 2 + 1];
    int wb = 0;
#pragma unroll
    for (int w = 0; w < WAVES - 1; ++w)
        if (w < wv) wb += __popcll(sm[w * 2]) + __popcll(sm[w * 2 + 1]);

    const uint64_t low = (1ull << lane) - 1ull;
    const int beforeE = __popcll(m0 & low) + __popcll(m1 & low);
    const bool v0 = (m0 >> lane) & 1ull;
    const bool v1 = (m1 >> lane) & 1ull;

    const size_t batchF = (size_t)b * kN * kC;
    const int rowBlk = sub * ROWS_PER_BLK + wv * 128 + 2 * lane;
    const int vcnt0 = blockBase + wb + beforeE;
    const int vcnt1 = vcnt0 + (v0 ? 1 : 0);

    if (v0) {
        const float2* r = (const float2*)(pc + batchF + (size_t)rowBlk * kC);
        float2* o = (float2*)(out + batchF + (size_t)vcnt0 * kC);
        o[0] = r[0]; o[1] = r[1]; o[2] = r[2];
    }
    if (v1) {
        const float2* r = (const float2*)(pc + batchF + (size_t)(rowBlk + 1) * kC);
        float2* o = (float2*)(out + batchF + (size_t)vcnt1 * kC);
        o[0] = r[0]; o[1] = r[1]; o[2] = r[2];
    }

    const int tail = kN - total;
    const int len  = (tail + BPB - 1) >> 8;
    const int r0 = total + sub * len;
    const int r1 = min(r0 + len, kN);
    if (r0 < r1) {
        float* base = out + batchF;
        const int f0 = r0 * 6, f1 = r1 * 6;
        if (tid == 0) {
            const float2 zz = make_float2(0.0f, 0.0f);
            if (f0 & 3) *(float2*)(base + f0) = zz;
            if (f1 & 3) *(float2*)(base + (f1 & ~3)) = zz;
        }
        const int a4 = (f0 + 3) >> 2;
        const int b4 = f1 >> 2;
        float4* o4 = (float4*)base;
        const float4 z4 = make_float4(0.0f, 0.0f, 0.0f, 0.0f);
        for (int i = a4 + tid; i < b4; i += TPB) o4[i] = z4;
    }
}

} // namespace

extern "C" void kernel_launch(void* const* d_in, const int* in_sizes, int n_in,
                              void* d_out, int out_size, void* d_ws, size_t ws_size,
                              hipStream_t stream) {
    const float* pc = (const float*)d_in[0];   // (32, 131072, 6) f32
    const float* tt = (const float*)d_in[1];   // (32, 4, 4) f32
    float* out = (float*)d_out;                // (32, 131072, 6) f32

    const size_t stagedBytes = (size_t)NBLK * ROWS_PER_BLK * kC * sizeof(float); // 100.7 MB
    const size_t cntBytes    = (size_t)NBLK * sizeof(int);

    if (ws_size >= stagedBytes + cntBytes) {
        float* staged = (float*)d_ws;
        int* blkCnt   = (int*)((char*)d_ws + stagedBytes);
        k_count_stage<<<NBLK, TPB, 0, stream>>>(pc, tt, staged, blkCnt);
        k_emit<<<NBLK, TPB, 0, stream>>>(staged, blkCnt, out);
    } else {
        uint64_t* masks = (uint64_t*)d_ws;
        int* blkCnt     = (int*)((char*)d_ws + (size_t)NBLK * 8 * sizeof(uint64_t));
        k_count<<<NBLK, TPB, 0, stream>>>(pc, tt, masks, blkCnt);
        k_scatter<<<NBLK, TPB, 0, stream>>>(pc, masks, blkCnt, out);
    }
}

// Round 9
// 37.012 us; speedup vs baseline: 1.2921x; 1.2921x over previous
//
#include <hip/hip_runtime.h>
#include <cstdint>

namespace {

constexpr int kB   = 32;            // batches
constexpr int kN   = 131072;        // points per batch
constexpr int kC   = 6;             // channels
constexpr int TPB  = 256;           // threads per block
constexpr int ROWS_PER_BLK = 512;   // 2 rows per thread
constexpr int BPB  = kN / ROWS_PER_BLK;   // 256 blocks per batch
constexpr int NBLK = kB * BPB;            // 8192 blocks total
constexpr int WAVES = TPB / 64;           // 4
constexpr int F4_PER_BLK = ROWS_PER_BLK * kC / 4;  // 768 float4 per block
constexpr int F2_PER_SLOT = ROWS_PER_BLK * kC / 2; // 1536 float2 per staged slot

__device__ __forceinline__ int waveSum(int v) {
#pragma unroll
    for (int off = 32; off; off >>= 1) v += __shfl_xor(v, off, 64);
    return v;
}

// ---------------- FAST PATH (ws >= ~101 MB): stage compacted rows ----------------

// Pass 1: dense coalesced float4 loads -> LDS -> row reassembly -> classify ->
// write per-block compacted valid rows to ws + per-block count.
__global__ __launch_bounds__(TPB) void k_count_stage(const float* __restrict__ pc,
                                                     const float* __restrict__ tt,
                                                     float* __restrict__ staged,
                                                     int* __restrict__ blkCnt) {
    const int blk  = blockIdx.x;
    const int b    = blk >> 8;          // blk / BPB
    const int tid  = threadIdx.x;
    const int lane = tid & 63;
    const int wv   = tid >> 6;

    const float* T = tt + b * 16;       // uniform -> scalar regs
    const float T0 = T[0], T1 = T[1], T2 = T[2],  T3  = T[3];
    const float T4 = T[4], T5 = T[5], T6 = T[6],  T7  = T[7];
    const float T8 = T[8], T9 = T[9], T10 = T[10], T11 = T[11];

    // Dense, fully-coalesced global reads (lane i -> consecutive 16 B).
    const float4* f4 = (const float4*)pc + (size_t)blk * F4_PER_BLK;
    const float4 qa = f4[tid];
    const float4 qb = f4[tid + 256];
    const float4 qc = f4[tid + 512];

    __shared__ float4 sb[F4_PER_BLK];
    sb[tid] = qa; sb[tid + 256] = qb; sb[tid + 512] = qc;
    __syncthreads();

    // Rows 2*tid, 2*tid+1 = float2[6*tid .. 6*tid+5]
    const float2* s2 = (const float2*)sb;
    const float2 r0a = s2[6 * tid],     r0b = s2[6 * tid + 1], r0c = s2[6 * tid + 2];
    const float2 r1a = s2[6 * tid + 3], r1b = s2[6 * tid + 4], r1c = s2[6 * tid + 5];

    // even row: x,y = r0a ; z,nx = r0b ; ny,nz = r0c
    const float ns0 = (r0b.y + r0c.x) + r0c.y;
    const float px0 = r0a.x * T0 + r0a.y * T4 + r0b.x * T8  + T3;
    const float py0 = r0a.x * T1 + r0a.y * T5 + r0b.x * T9  + T7;
    const float pz0 = r0a.x * T2 + r0a.y * T6 + r0b.x * T10 + T11;
    const bool v0 = (px0 * px0 + py0 * py0 < 1.0f) && (pz0 < 1.0f) && (ns0 != 0.0f);

    // odd row: x,y = r1a ; z,nx = r1b ; ny,nz = r1c
    const float ns1 = (r1b.y + r1c.x) + r1c.y;
    const float px1 = r1a.x * T0 + r1a.y * T4 + r1b.x * T8  + T3;
    const float py1 = r1a.x * T1 + r1a.y * T5 + r1b.x * T9  + T7;
    const float pz1 = r1a.x * T2 + r1a.y * T6 + r1b.x * T10 + T11;
    const bool v1 = (px1 * px1 + py1 * py1 < 1.0f) && (pz1 < 1.0f) && (ns1 != 0.0f);

    const uint64_t m0 = __ballot(v0);   // rows wv*128 + 2*lane
    const uint64_t m1 = __ballot(v1);   // rows wv*128 + 2*lane + 1

    __shared__ uint64_t sm[WAVES * 2];
    if (lane == 0) { sm[wv * 2] = m0; sm[wv * 2 + 1] = m1; }
    __syncthreads();

    if (wv == 0) {
        int v = (lane < 8) ? __popcll(sm[lane]) : 0;
        v = waveSum(v);
        if (lane == 0) blkCnt[blk] = v;
    }

    // In-block stable compaction rank
    int wb = 0;
#pragma unroll
    for (int w = 0; w < WAVES - 1; ++w)
        if (w < wv) wb += __popcll(sm[w * 2]) + __popcll(sm[w * 2 + 1]);
    const uint64_t low = (1ull << lane) - 1ull;
    const int beforeE = __popcll(m0 & low) + __popcll(m1 & low);
    const int rk0 = wb + beforeE;
    const int rk1 = rk0 + (v0 ? 1 : 0);

    float2* st = (float2*)(staged + (size_t)blk * (ROWS_PER_BLK * kC));
    if (v0) { float2* o = st + rk0 * 3; o[0] = r0a; o[1] = r0b; o[2] = r0c; }
    if (v1) { float2* o = st + rk1 * 3; o[0] = r1a; o[1] = r1b; o[2] = r1c; }
}

// Pass 2 (output-centric): each block owns output rows [sub*512,(sub+1)*512).
// Gather valid rows from staged (binary search over batch prefix, ~8% of
// threads), assemble the block's output tile in LDS, then store it as one
// dense 16B-aligned full-line float4 stream (f4[tid], f4[tid+256], f4[tid+512]).
__global__ __launch_bounds__(TPB) void k_emit(const float* __restrict__ staged,
                                              const int* __restrict__ blkCnt,
                                              float* __restrict__ out) {
    const int blk  = blockIdx.x;
    const int b    = blk >> 8;
    const int sub  = blk & (BPB - 1);
    const int tid  = threadIdx.x;
    const int lane = tid & 63;
    const int wv   = tid >> 6;

    __shared__ int pre[BPB];        // exclusive prefix of per-block counts
    __shared__ int wsum[WAVES];
    __shared__ int s_tot;
    __shared__ float4 xb[F4_PER_BLK];   // output image of this block's 512 rows

    // Inclusive wave scan of the 256 counts, then cross-wave offsets.
    const int c = blkCnt[b * BPB + tid];
    int v = c;
#pragma unroll
    for (int off = 1; off < 64; off <<= 1) {
        const int u = __shfl_up(v, off, 64);
        if (lane >= off) v += u;
    }
    if (lane == 63) wsum[wv] = v;
    __syncthreads();
    int wbase = 0;
#pragma unroll
    for (int w = 0; w < WAVES - 1; ++w)
        if (w < wv) wbase += wsum[w];
    pre[tid] = wbase + v - c;                 // exclusive prefix
    if (tid == TPB - 1) s_tot = wbase + v;    // batch total
    __syncthreads();
    const int total = s_tot;

    const int r0 = sub * ROWS_PER_BLK + 2 * tid;     // thread's two rows
    float2 val[6];
#pragma unroll
    for (int e = 0; e < 2; ++e) {
        const int r = r0 + e;
        float2 x0 = make_float2(0.0f, 0.0f), x1 = x0, x2 = x0;
        if (r < total) {
            int lo = 0, hi = BPB - 1;
#pragma unroll
            for (int it = 0; it < 8; ++it) {          // ceil(log2(256)) = 8
                const int mid = (lo + hi + 1) >> 1;
                if (pre[mid] <= r) lo = mid; else hi = mid - 1;
            }
            const int local = r - pre[lo];
            const float2* s = (const float2*)staged
                            + (size_t)(b * BPB + lo) * F2_PER_SLOT + (size_t)local * 3;
            x0 = s[0]; x1 = s[1]; x2 = s[2];
        }
        val[3 * e]     = x0;
        val[3 * e + 1] = x1;
        val[3 * e + 2] = x2;
    }

    // LDS exchange: drop the two rows into the tile image...
    float2* x2l = (float2*)xb;
#pragma unroll
    for (int k = 0; k < 6; ++k) x2l[6 * tid + k] = val[k];
    __syncthreads();

    // ...then one dense aligned full-line store stream.
    float4* o4 = (float4*)(out + ((size_t)b * kN + (size_t)sub * ROWS_PER_BLK) * kC);
    o4[tid]       = xb[tid];
    o4[tid + 256] = xb[tid + 256];
    o4[tid + 512] = xb[tid + 512];
}

// ---------------- FALLBACK PATH (small ws): R6 mask-based kernels ----------------

__global__ __launch_bounds__(TPB) void k_count(const float* __restrict__ pc,
                                               const float* __restrict__ tt,
                                               uint64_t* __restrict__ masks,
                                               int* __restrict__ blkCnt) {
    const int blk  = blockIdx.x;
    const int b    = blk >> 8;
    const int tid  = threadIdx.x;
    const int lane = tid & 63;
    const int wv   = tid >> 6;

    const float* T = tt + b * 16;
    const float T0 = T[0], T1 = T[1], T2 = T[2],  T3  = T[3];
    const float T4 = T[4], T5 = T[5], T6 = T[6],  T7  = T[7];
    const float T8 = T[8], T9 = T[9], T10 = T[10], T11 = T[11];

    const float4* f4 = (const float4*)pc + (size_t)blk * F4_PER_BLK;
    const float4 q0 = f4[3 * tid];
    const float4 q1 = f4[3 * tid + 1];
    const float4 q2 = f4[3 * tid + 2];

    const float ns0 = (q0.w + q1.x) + q1.y;
    const float px0 = q0.x * T0 + q0.y * T4 + q0.z * T8  + T3;
    const float py0 = q0.x * T1 + q0.y * T5 + q0.z * T9  + T7;
    const float pz0 = q0.x * T2 + q0.y * T6 + q0.z * T10 + T11;
    const bool v0 = (px0 * px0 + py0 * py0 < 1.0f) && (pz0 < 1.0f) && (ns0 != 0.0f);

    const float ns1 = (q2.y + q2.z) + q2.w;
    const float px1 = q1.z * T0 + q1.w * T4 + q2.x * T8  + T3;
    const float py1 = q1.z * T1 + q1.w * T5 + q2.x * T9  + T7;
    const float pz1 = q1.z * T2 + q1.w * T6 + q2.x * T10 + T11;
    const bool v1 = (px1 * px1 + py1 * py1 < 1.0f) && (pz1 < 1.0f) && (ns1 != 0.0f);

    const uint64_t m0 = __ballot(v0);
    const uint64_t m1 = __ballot(v1);

    __shared__ uint64_t sm[WAVES * 2];
    if (lane == 0) {
        sm[wv * 2]     = m0;
        sm[wv * 2 + 1] = m1;
        masks[(size_t)blk * 8 + wv * 2]     = m0;
        masks[(size_t)blk * 8 + wv * 2 + 1] = m1;
    }
    __syncthreads();
    if (wv == 0) {
        int v = (lane < 8) ? __popcll(sm[lane]) : 0;
        v = waveSum(v);
        if (lane == 0) blkCnt[blk] = v;
    }
}

__global__ __launch_bounds__(TPB) void k_scatter(const float* __restrict__ pc,
                                                 const uint64_t* __restrict__ masks,
                                                 const int* __restrict__ blkCnt,
                                                 float* __restrict__ out) {
    const int blk  = blockIdx.x;
    const int b    = blk >> 8;
    const int sub  = blk & (BPB - 1);
    const int tid  = threadIdx.x;
    const int lane = tid & 63;
    const int wv   = tid >> 6;

    __shared__ uint64_t sm[8];
    __shared__ int sRed[2 * WAVES];

    if (tid < 8) sm[tid] = masks[(size_t)blk * 8 + tid];

    const int c = blkCnt[b * BPB + tid];
    const int pw = waveSum((tid < sub) ? c : 0);
    const int tw = waveSum(c);
    if (lane == 0) { sRed[wv] = pw; sRed[WAVES + wv] = tw; }
    __syncthreads();
    const int blockBase = (sRed[0] + sRed[1]) + (sRed[2] + sRed[3]);
    const int total     = (sRed[4] + sRed[5]) + (sRed[6] + sRed[7]);

    const uint64_t m0 = sm[wv * 2], m1 = sm[wv * 2 + 1];
    int wb = 0;
#pragma unroll
    for (int w = 0; w < WAVES - 1; ++w)
        if (w < wv) wb += __popcll(sm[w * 2]) + __popcll(sm[w * 2 + 1]);

    const uint64_t low = (1ull << lane) - 1ull;
    const int beforeE = __popcll(m0 & low) + __popcll(m1 & low);
    const bool v0 = (m0 >> lane) & 1ull;
    const bool v1 = (m1 >> lane) & 1ull;

    const size_t batchF = (size_t)b * kN * kC;
    const int rowBlk = sub * ROWS_PER_BLK + wv * 128 + 2 * lane;
    const int vcnt0 = blockBase + wb + beforeE;
    const int vcnt1 = vcnt0 + (v0 ? 1 : 0);

    if (v0) {
        const float2* r = (const float2*)(pc + batchF + (size_t)rowBlk * kC);
        float2* o = (float2*)(out + batchF + (size_t)vcnt0 * kC);
        o[0] = r[0]; o[1] = r[1]; o[2] = r[2];
    }
    if (v1) {
        const float2* r = (const float2*)(pc + batchF + (size_t)(rowBlk + 1) * kC);
        float2* o = (float2*)(out + batchF + (size_t)vcnt1 * kC);
        o[0] = r[0]; o[1] = r[1]; o[2] = r[2];
    }

    const int tail = kN - total;
    const int len  = (tail + BPB - 1) >> 8;
    const int r0 = total + sub * len;
    const int r1 = min(r0 + len, kN);
    if (r0 < r1) {
        float* base = out + batchF;
        const int f0 = r0 * 6, f1 = r1 * 6;
        if (tid == 0) {
            const float2 zz = make_float2(0.0f, 0.0f);
            if (f0 & 3) *(float2*)(base + f0) = zz;
            if (f1 & 3) *(float2*)(base + (f1 & ~3)) = zz;
        }
        const int a4 = (f0 + 3) >> 2;
        const int b4 = f1 >> 2;
        float4* o4 = (float4*)base;
        const float4 z4 = make_float4(0.0f, 0.0f, 0.0f, 0.0f);
        for (int i = a4 + tid; i < b4; i += TPB) o4[i] = z4;
    }
}

} // namespace

extern "C" void kernel_launch(void* const* d_in, const int* in_sizes, int n_in,
                              void* d_out, int out_size, void* d_ws, size_t ws_size,
                              hipStream_t stream) {
    const float* pc = (const float*)d_in[0];   // (32, 131072, 6) f32
    const float* tt = (const float*)d_in[1];   // (32, 4, 4) f32
    float* out = (float*)d_out;                // (32, 131072, 6) f32

    const size_t stagedBytes = (size_t)NBLK * ROWS_PER_BLK * kC * sizeof(float); // 100.7 MB
    const size_t cntBytes    = (size_t)NBLK * sizeof(int);

    if (ws_size >= stagedBytes + cntBytes) {
        float* staged = (float*)d_ws;
        int* blkCnt   = (int*)((char*)d_ws + stagedBytes);
        k_count_stage<<<NBLK, TPB, 0, stream>>>(pc, tt, staged, blkCnt);
        k_emit<<<NBLK, TPB, 0, stream>>>(staged, blkCnt, out);
    } else {
        uint64_t* masks = (uint64_t*)d_ws;
        int* blkCnt     = (int*)((char*)d_ws + (size_t)NBLK * 8 * sizeof(uint64_t));
        k_count<<<NBLK, TPB, 0, stream>>>(pc, tt, masks, blkCnt);
        k_scatter<<<NBLK, TPB, 0, stream>>>(pc, masks, blkCnt, out);
    }
}